// Round 21
// baseline (157.358 us; speedup 1.0000x reference)
//
#include <hip/hip_runtime.h>
#include <hip/hip_bf16.h>
#include <cstdint>

typedef __bf16 bf16x8 __attribute__((ext_vector_type(8)));
typedef float f32x4 __attribute__((ext_vector_type(4)));
typedef float f32x16 __attribute__((ext_vector_type(16)));
typedef unsigned int u32;
typedef unsigned short u16;
typedef u32 u32x4 __attribute__((ext_vector_type(4)));

#define AS1 __attribute__((address_space(1)))
#define AS3 __attribute__((address_space(3)))

static __device__ __forceinline__ void gld16(const void* g, void* l) {
  __builtin_amdgcn_global_load_lds((const AS1 u32*)g, (AS3 u32*)l, 16, 0, 0);
}
static __device__ __forceinline__ u16 f2b(float f) {
  return __builtin_bit_cast(u16, __float2bfloat16(f));
}
static __device__ __forceinline__ float b2f(u16 u) {
  return __bfloat162float(__builtin_bit_cast(__hip_bfloat16, u));
}
// one-instruction pack: lo = bf16(a), hi = bf16(b)
static __device__ __forceinline__ u32 cvtpk(float a, float b) {
  u32 r;
  asm("v_cvt_pk_bf16_f32 %0, %1, %2" : "=v"(r) : "v"(a), "v"(b));
  return r;
}

// ---------------- prep: RoPE tables (packed float2) + fp32->bf16 convert ----------------
// blocks 0..511: cst[t][i] = {cos,sin} (131072 items). blocks 512+: convert (3670016 f4).
__global__ __launch_bounds__(256) void k_prep(
    const float* __restrict__ x, const float* __restrict__ wq,
    const float* __restrict__ wk, const float* __restrict__ wv,
    u16* __restrict__ xb, u16* __restrict__ wqb,
    u16* __restrict__ wkb, u16* __restrict__ wvb,
    float2* __restrict__ cst) {
  const int idx = blockIdx.x * 256 + threadIdx.x;
  if (idx < 131072) {
    const int t = idx >> 6, i = idx & 63;
    const float inv = exp2f(-(float)(2 * i) * (13.287712379549449f / 128.0f));
    const float f = (float)t * inv;
    cst[idx] = make_float2(cosf(f), sinf(f));
    return;
  }
  const int i4 = idx - 131072;              // 0 .. 3670015
  const int e = i4 * 4;
  const float* s; u16* d;
  if (e < 8388608)        { s = x  + e;              d = xb  + e; }
  else if (e < 12582912)  { int o = e - 8388608;  s = wq + o; d = wqb + o; }
  else if (e < 13631488)  { int o = e - 12582912; s = wk + o; d = wkb + o; }
  else                    { int o = e - 13631488; s = wv + o; d = wvb + o; }
  const float4 v = *(const float4*)s;
  ushort4 o4;
  o4.x = f2b(v.x); o4.y = f2b(v.y); o4.z = f2b(v.z); o4.w = f2b(v.w);
  *(ushort4*)d = o4;
}

// ---------------- fused QKV projection GEMM (bf16 MFMA, m97 structure) ----------------
// K-loop/epilogue BYTE-IDENTICAL to round-11/18. Only change: XCD-aware block
// remap (T1, x-chunked): grid linearized to 768; xcd = lin&7 owns M-tiles
// 4*xcd..4*xcd+3 across all 24 N-panels -> per-XCD L2 working set = 4 A-panels
// (2MB, resident) + current B-panel (512KB, reused by 4 consecutive blocks).
// vT is written with token-index bits 2<->3 swapped (within each 16-token group).
__global__ __launch_bounds__(256) void k_gemm(
    const u16* __restrict__ xb, const u16* __restrict__ wqb,
    const u16* __restrict__ wkb, const u16* __restrict__ wvb,
    u16* __restrict__ qb, u16* __restrict__ kb, u16* __restrict__ vT) {
  __shared__ __align__(16) char smA[8192];   // [128][32] bf16, source-chunk-swizzled
  __shared__ __align__(16) char smB[8192];
  const int tid = threadIdx.x;
  const int w = tid >> 6, l = tid & 63;
  const int lm = l & 15, g = l >> 4;
  const int lin = blockIdx.x;                // 0..767
  const int xcd = lin & 7;
  const int kk2 = lin >> 3;                  // 0..95
  const int bx  = xcd * 4 + (kk2 & 3);       // M-tile 0..31
  const int m0 = bx << 7;
  const int j = kk2 >> 2;                    // N-panel 0..23
  const u16* W; u16* dst; int n0, ldc, vmode;
  if (j < 16)      { W = wqb; dst = qb; n0 = j << 7;        ldc = 2048; vmode = 0; }
  else if (j < 20) { W = wkb; dst = kb; n0 = (j - 16) << 7; ldc = 512;  vmode = 0; }
  else             { W = wvb; dst = vT; n0 = (j - 20) << 7; ldc = 0;    vmode = 1; }

  const int srow = w * 16 + (l >> 2);
  const int scol = l & 3;

  f32x4 acc[4][4];
  #pragma unroll
  for (int a = 0; a < 4; ++a)
    #pragma unroll
    for (int bb = 0; bb < 4; ++bb) { f32x4 zz = {0.f, 0.f, 0.f, 0.f}; acc[a][bb] = zz; }

  const int wm = (w >> 1) << 6, wn = (w & 1) << 6;

  for (int k0 = 0; k0 < 2048; k0 += 32) {
    #pragma unroll
    for (int i = 0; i < 2; ++i) {
      const int r = srow + (i << 6);
      const int sc = (scol ^ (r & 3)) << 3;
      gld16(xb + (m0 + r) * 2048 + k0 + sc, smA + ((i * 4 + w) << 10));
      gld16(W  + (n0 + r) * 2048 + k0 + sc, smB + ((i * 4 + w) << 10));
    }
    __syncthreads();
    bf16x8 af[4], bfr[4];
    #pragma unroll
    for (int mt = 0; mt < 4; ++mt) {
      const int row = wm + mt * 16 + lm;
      af[mt] = *(const bf16x8*)(smA + row * 64 + ((g ^ (row & 3)) << 4));
    }
    #pragma unroll
    for (int nt = 0; nt < 4; ++nt) {
      const int row = wn + nt * 16 + lm;
      bfr[nt] = *(const bf16x8*)(smB + row * 64 + ((g ^ (row & 3)) << 4));
    }
    #pragma unroll
    for (int mt = 0; mt < 4; ++mt)
      #pragma unroll
      for (int nt = 0; nt < 4; ++nt)
        acc[mt][nt] = __builtin_amdgcn_mfma_f32_16x16x32_bf16(af[mt], bfr[nt], acc[mt][nt], 0, 0, 0);
    __syncthreads();
  }

  const int gs = ((g & 1) << 1) | (g >> 1);   // token-index bit2<->bit3 swap for vT
  #pragma unroll
  for (int mt = 0; mt < 4; ++mt) {
    #pragma unroll
    for (int nt = 0; nt < 4; ++nt) {
      const int n = n0 + wn + nt * 16 + lm;
      #pragma unroll
      for (int r = 0; r < 4; ++r) {
        const u16 hv = f2b(acc[mt][nt][r]);
        if (!vmode) {
          const int mq = m0 + wm + mt * 16 + g * 4 + r;
          dst[mq * ldc + n] = hv;
        } else {
          const int mv = m0 + wm + mt * 16 + gs * 4 + r;
          dst[n * 4096 + mv] = hv;
        }
      }
    }
  }
}

// ---------------- RMSNorm + RoPE in-place on K ONLY (16384 items) ----------------
// (q's norm+rope is folded into k_attn's Q-load, in-register.)
__global__ __launch_bounds__(256) void k_normrope(u16* __restrict__ kb,
                                                  const float2* __restrict__ cst) {
  const int item = blockIdx.x * 4 + (threadIdx.x >> 6);
  const int l = threadIdx.x & 63;
  u16* p = kb + item * 128;
  const int tpos = (item >> 2) & 2047;
  const float f1 = b2f(p[l]);
  const float f2 = b2f(p[l + 64]);
  float ss = f1 * f1 + f2 * f2;
  #pragma unroll
  for (int d = 1; d < 64; d <<= 1) ss += __shfl_xor(ss, d);
  const float rn = rsqrtf(ss * (1.0f / 128.0f) + 1.1920928955078125e-07f);
  const float2 cs = cst[tpos * 64 + l];
  const float x1 = f1 * rn, x2 = f2 * rn;
  p[l]      = f2b(x1 * cs.x + x2 * cs.y);
  p[l + 64] = f2b(x2 * cs.x - x1 * cs.y);
}

// ---------------- causal GQA flash attention: no-max softmax + kv-split, -------------
// ---------------- q-RMSNorm+RoPE folded into Q-load (packed float2 tables) -----------
// Lane (lq,hi) holds q dims {16c+8hi+j}; RoPE partner d<->d+64 = fragment c<->c+4
// (same lane). ss needs only shfl_xor(32). q scaled by rn*log2(e)/sqrt(128) here,
// so scores stay bounded (|s|<=16.4) and softmax needs no max.
// grid (1024): bid&7 = (b,hkv) XCD-local; ring-complementary tau map; 2-wave
// blocks, 32KB single-buffer LDS -> 4 blocks/CU. kv-split A/B additive streams.
__global__ __launch_bounds__(128) void k_attn(
    const u16* __restrict__ qb, const u16* __restrict__ kb,
    const u16* __restrict__ vT, const float2* __restrict__ cst,
    float* __restrict__ out) {
  __shared__ __align__(16) char lds[32768];   // [stream][K 8K | V 8K]
  const int tid = threadIdx.x;
  const int l = tid & 63;
  const int w = tid >> 6;          // wave 0/1 -> q offset 32*w
  const int lq = l & 31;
  const int hi = l >> 5;

  const int bid = blockIdx.x;
  const int cxc = bid & 7;
  const int bb  = cxc >> 2, hkv = cxc & 3;
  const int hsub = (bid >> 3) & 3;
  const int h   = hkv * 4 + hsub;
  const int g   = bid >> 5;              // 0..31, ring = g>>3
  const int a   = g & 7;
  const int tau = (g < 8) ? (31 - a) : (g < 16) ? (16 + a) : (g < 24) ? (15 - a) : a;
  const int RH  = tau + 1;               // double-rounds (each = 2 kv-tiles of 32)
  const int half = RH * 32;              // stream B kv offset

  const u16* kbase = kb + ((size_t)bb * 2048) * 512 + hkv * 128;
  const u16* vbase = vT + ((size_t)(hkv * 128)) * 4096 + (size_t)bb * 2048;
  const u16* qhb   = qb + ((size_t)bb * 2048) * 2048 + h * 128;

  const int krow_t = tid >> 4, kch = tid & 15;   // K staging coords
  const int vrow_t = tid >> 2, vch = tid & 3;    // V staging coords

  const int qabs = tau * 64 + w * 32 + lq;
  const int qmin = tau * 64 + w * 32;

  // ---- Q load + in-register RMSNorm + RoPE (once per block) ----
  bf16x8 qf[8];
  {
    const u16* qp = qhb + (size_t)qabs * 2048;
    bf16x8 qraw[8];
    #pragma unroll
    for (int c = 0; c < 8; ++c) qraw[c] = *(const bf16x8*)(qp + c * 16 + hi * 8);
    float ss = 0.f;
    #pragma unroll
    for (int c = 0; c < 8; ++c)
      #pragma unroll
      for (int jj = 0; jj < 8; ++jj) {
        const float v = (float)qraw[c][jj];
        ss += v * v;
      }
    ss += __shfl_xor(ss, 32);
    const float rn = rsqrtf(ss * (1.0f / 128.0f) + 1.1920928955078125e-07f)
                   * 0.12751742f;   // log2(e)/sqrt(128)
    const float2* cs2 = cst + (size_t)qabs * 64;
    #pragma unroll
    for (int c = 0; c < 4; ++c) {
      u32 wlo[4], whi[4];
      #pragma unroll
      for (int m = 0; m < 4; ++m) {
        float ylo[2], yhi[2];
        #pragma unroll
        for (int p2 = 0; p2 < 2; ++p2) {
          const int jj = 2 * m + p2;
          const int i = c * 16 + hi * 8 + jj;     // 0..63
          const float2 cs = cs2[i];
          const float xlo = (float)qraw[c][jj];
          const float xhi = (float)qraw[c + 4][jj];
          ylo[p2] = (xlo * cs.x + xhi * cs.y) * rn;
          yhi[p2] = (xhi * cs.x - xlo * cs.y) * rn;
        }
        wlo[m] = cvtpk(ylo[0], ylo[1]);
        whi[m] = cvtpk(yhi[0], yhi[1]);
      }
      u32x4 vlo = {wlo[0], wlo[1], wlo[2], wlo[3]};
      u32x4 vhi = {whi[0], whi[1], whi[2], whi[3]};
      qf[c]     = __builtin_bit_cast(bf16x8, vlo);
      qf[c + 4] = __builtin_bit_cast(bf16x8, vhi);
    }
  }

  f32x16 oacc[4], sA, sB;
  #pragma unroll
  for (int dt = 0; dt < 4; ++dt)
    #pragma unroll
    for (int e = 0; e < 16; ++e) oacc[dt][e] = 0.f;
  float llA = 0.f, llB = 0.f;

  // stage one stream's kv-tile (16 KB: K 8K + V 8K), 128 threads x 8 gld16
  auto STAGE = [&](int st, int jb2) {
    char* bK = lds + st * 16384;
    char* bV = bK + 8192;
    #pragma unroll
    for (int u = 0; u < 4; ++u) {
      const int kr = u * 8 + krow_t;
      gld16(kbase + (size_t)(jb2 + kr) * 512 + ((kch ^ (kr & 15)) << 3),
            bK + u * 2048 + tid * 16);
      // V paired-row layout: slot (R0, C0) holds V[2*R0 + (cp>>2)][8*(cp&3) ..]
      const int R0 = u * 16 + (vrow_t >> 1);          // 0..63
      const int C0 = ((vrow_t & 1) << 2) + vch;       // 0..7
      const int cp = C0 ^ (R0 & 7);
      const int vd = 2 * R0 + (cp >> 2);              // d row 0..127
      gld16(vbase + (size_t)vd * 4096 + jb2 + ((cp & 3) << 3),
            bV + u * 2048 + tid * 16);
    }
  };

  STAGE(0, 0);
  STAGE(1, half);
  __syncthreads();

  for (int r = 0; r < RH; ++r) {
    // ---- QK^T for both streams (independent MFMA chains) ----
    #pragma unroll
    for (int e = 0; e < 16; ++e) { sA[e] = 0.f; sB[e] = 0.f; }
    const char* skA = lds;
    const char* skB = lds + 16384;
    #pragma unroll
    for (int c = 0; c < 8; ++c) {
      const int ch = ((2 * c + hi) ^ (lq & 15)) << 4;
      const bf16x8 kfA = *(const bf16x8*)(skA + lq * 256 + ch);
      const bf16x8 kfB = *(const bf16x8*)(skB + lq * 256 + ch);
      sA = __builtin_amdgcn_mfma_f32_32x32x16_bf16(kfA, qf[c], sA, 0, 0, 0);
      sB = __builtin_amdgcn_mfma_f32_32x32x16_bf16(kfB, qf[c], sB, 0, 0, 0);
    }

    // ---- no-max softmax: p = exp2(s) (|s| <= 16.4 by RMS-norm bound) ----
    const int jbA = r * 32;
    const int jbB = half + r * 32;
    if (jbA + 31 > qmin) {
      #pragma unroll
      for (int e = 0; e < 16; ++e) {
        const int kvl = (e & 3) + ((e >> 2) << 3) + (hi << 2);
        if (jbA + kvl > qabs) sA[e] = -1e30f;
      }
    }
    if (jbB + 31 > qmin) {
      #pragma unroll
      for (int e = 0; e < 16; ++e) {
        const int kvl = (e & 3) + ((e >> 2) << 3) + (hi << 2);
        if (jbB + kvl > qabs) sB[e] = -1e30f;
      }
    }
    float rA = 0.f, rB = 0.f;
    #pragma unroll
    for (int e = 0; e < 16; e += 4) {
      const float a0 = exp2f(sA[e]),     a1 = exp2f(sA[e + 1]);
      const float a2 = exp2f(sA[e + 2]), a3 = exp2f(sA[e + 3]);
      const float b0 = exp2f(sB[e]),     b1 = exp2f(sB[e + 1]);
      const float b2 = exp2f(sB[e + 2]), b3 = exp2f(sB[e + 3]);
      sA[e] = a0; sA[e + 1] = a1; sA[e + 2] = a2; sA[e + 3] = a3;
      sB[e] = b0; sB[e + 1] = b1; sB[e + 2] = b2; sB[e + 3] = b3;
      rA += (a0 + a1) + (a2 + a3);
      rB += (b0 + b1) + (b2 + b3);
    }
    llA += rA; llB += rB;

    // ---- PV for both streams into shared oacc (additive merge) ----
    // Exchange-free: B-fragment = lane's own P values in order (vT pre-permuted).
    const char* svA = lds + 8192;
    const char* svB = lds + 16384 + 8192;
    #pragma unroll
    for (int cc = 0; cc < 2; ++cc) {
      const int c8 = cc * 8;
      u32x4 bwA, bwB;
      bwA.x = cvtpk(sA[c8 + 0], sA[c8 + 1]);
      bwA.y = cvtpk(sA[c8 + 2], sA[c8 + 3]);
      bwA.z = cvtpk(sA[c8 + 4], sA[c8 + 5]);
      bwA.w = cvtpk(sA[c8 + 6], sA[c8 + 7]);
      bwB.x = cvtpk(sB[c8 + 0], sB[c8 + 1]);
      bwB.y = cvtpk(sB[c8 + 2], sB[c8 + 3]);
      bwB.z = cvtpk(sB[c8 + 4], sB[c8 + 5]);
      bwB.w = cvtpk(sB[c8 + 6], sB[c8 + 7]);
      const bf16x8 pfA = __builtin_bit_cast(bf16x8, bwA);
      const bf16x8 pfB = __builtin_bit_cast(bf16x8, bwB);
      #pragma unroll
      for (int dt = 0; dt < 4; ++dt) {
        const int vrow = dt * 16 + (lq >> 1);
        const int cpre = ((lq & 1) << 2) + 2 * cc + hi;
        const int chv = (cpre ^ (vrow & 7)) << 4;
        const bf16x8 vfA = *(const bf16x8*)(svA + vrow * 128 + chv);
        oacc[dt] = __builtin_amdgcn_mfma_f32_32x32x16_bf16(vfA, pfA, oacc[dt], 0, 0, 0);
      }
      #pragma unroll
      for (int dt = 0; dt < 4; ++dt) {
        const int vrow = dt * 16 + (lq >> 1);
        const int cpre = ((lq & 1) << 2) + 2 * cc + hi;
        const int chv = (cpre ^ (vrow & 7)) << 4;
        const bf16x8 vfB = *(const bf16x8*)(svB + vrow * 128 + chv);
        oacc[dt] = __builtin_amdgcn_mfma_f32_32x32x16_bf16(vfB, pfB, oacc[dt], 0, 0, 0);
      }
    }

    // ---- restage (single buffer): wait for readers, stage, wait for data ----
    if (r + 1 < RH) {
      __syncthreads();                 // all waves done reading this round
      STAGE(0, (r + 1) * 32);
      STAGE(1, half + (r + 1) * 32);
      __syncthreads();                 // vmcnt(0) drain + visibility
    }
  }

  // ---- epilogue: merge streams + halves, write O ----
  float ll = llA + llB;
  ll += __shfl_xor(ll, 32);
  const float inv = 1.0f / ll;
  float* ob = out + ((size_t)(bb * 2048 + qabs)) * 2048 + h * 128;
  #pragma unroll
  for (int dt = 0; dt < 4; ++dt)
    #pragma unroll
    for (int qd = 0; qd < 4; ++qd) {
      float4 o4;
      o4.x = oacc[dt][qd * 4 + 0] * inv;
      o4.y = oacc[dt][qd * 4 + 1] * inv;
      o4.z = oacc[dt][qd * 4 + 2] * inv;
      o4.w = oacc[dt][qd * 4 + 3] * inv;
      *(float4*)(ob + dt * 32 + qd * 8 + hi * 4) = o4;
    }
}

extern "C" void kernel_launch(void* const* d_in, const int* in_sizes, int n_in,
                              void* d_out, int out_size, void* d_ws, size_t ws_size,
                              hipStream_t stream) {
  const float* x  = (const float*)d_in[0];
  const float* wq = (const float*)d_in[1];
  const float* wk = (const float*)d_in[2];
  const float* wv = (const float*)d_in[3];
  float* out = (float*)d_out;
  char* ws = (char*)d_ws;

  float2* cst = (float2*)(ws);                // 1 MB packed {cos,sin}
  u16* xb  = (u16*)(ws + 1048576);            // 16 MB
  u16* wqb = (u16*)(ws + 17825792);           // 8 MB
  u16* wkb = (u16*)(ws + 26214400);           // 2 MB
  u16* wvb = (u16*)(ws + 28311552);           // 2 MB
  u16* qb  = (u16*)(ws + 30408704);           // 16 MB
  u16* kb  = (u16*)(ws + 47185920);           // 4 MB
  u16* vT  = (u16*)(ws + 51380224);           // 4 MB  -> total 55574528
  if (ws_size < 55574528) return;

  k_prep    <<<dim3(14848), dim3(256), 0, stream>>>(x, wq, wk, wv, xb, wqb, wkb, wvb, cst);
  k_gemm    <<<dim3(768),   dim3(256), 0, stream>>>(xb, wqb, wkb, wvb, qb, kb, vT);
  k_normrope<<<dim3(4096),  dim3(256), 0, stream>>>(kb, cst);
  k_attn    <<<dim3(1024),  dim3(128), 0, stream>>>(qb, kb, vT, cst, out);
}

// Round 22
// 155.351 us; speedup vs baseline: 1.0129x; 1.0129x over previous
//
#include <hip/hip_runtime.h>
#include <hip/hip_bf16.h>
#include <cstdint>

typedef __bf16 bf16x8 __attribute__((ext_vector_type(8)));
typedef float f32x4 __attribute__((ext_vector_type(4)));
typedef float f32x16 __attribute__((ext_vector_type(16)));
typedef unsigned int u32;
typedef unsigned short u16;
typedef u32 u32x4 __attribute__((ext_vector_type(4)));

#define AS1 __attribute__((address_space(1)))
#define AS3 __attribute__((address_space(3)))

static __device__ __forceinline__ void gld16(const void* g, void* l) {
  __builtin_amdgcn_global_load_lds((const AS1 u32*)g, (AS3 u32*)l, 16, 0, 0);
}
static __device__ __forceinline__ u16 f2b(float f) {
  return __builtin_bit_cast(u16, __float2bfloat16(f));
}
static __device__ __forceinline__ float b2f(u16 u) {
  return __bfloat162float(__builtin_bit_cast(__hip_bfloat16, u));
}
// one-instruction pack: lo = bf16(a), hi = bf16(b)
static __device__ __forceinline__ u32 cvtpk(float a, float b) {
  u32 r;
  asm("v_cvt_pk_bf16_f32 %0, %1, %2" : "=v"(r) : "v"(a), "v"(b));
  return r;
}

// ---------------- prep: RoPE tables (packed float2) + fp32->bf16 convert ----------------
// blocks 0..511: cst[t][i] = {cos,sin} (131072 items). blocks 512+: convert (3670016 f4).
__global__ __launch_bounds__(256) void k_prep(
    const float* __restrict__ x, const float* __restrict__ wq,
    const float* __restrict__ wk, const float* __restrict__ wv,
    u16* __restrict__ xb, u16* __restrict__ wqb,
    u16* __restrict__ wkb, u16* __restrict__ wvb,
    float2* __restrict__ cst) {
  const int idx = blockIdx.x * 256 + threadIdx.x;
  if (idx < 131072) {
    const int t = idx >> 6, i = idx & 63;
    const float inv = exp2f(-(float)(2 * i) * (13.287712379549449f / 128.0f));
    const float f = (float)t * inv;
    cst[idx] = make_float2(cosf(f), sinf(f));
    return;
  }
  const int i4 = idx - 131072;              // 0 .. 3670015
  const int e = i4 * 4;
  const float* s; u16* d;
  if (e < 8388608)        { s = x  + e;              d = xb  + e; }
  else if (e < 12582912)  { int o = e - 8388608;  s = wq + o; d = wqb + o; }
  else if (e < 13631488)  { int o = e - 12582912; s = wk + o; d = wkb + o; }
  else                    { int o = e - 13631488; s = wv + o; d = wvb + o; }
  const float4 v = *(const float4*)s;
  ushort4 o4;
  o4.x = f2b(v.x); o4.y = f2b(v.y); o4.z = f2b(v.z); o4.w = f2b(v.w);
  *(ushort4*)d = o4;
}

// ---------------- fused QKV projection GEMM (bf16 MFMA, m97 structure) ----------------
// K-loop/epilogue BYTE-IDENTICAL to round-11/18; XCD-chunked block remap (neutral,
// kept). vT written with token-index bits 2<->3 swapped (within 16-token groups).
__global__ __launch_bounds__(256) void k_gemm(
    const u16* __restrict__ xb, const u16* __restrict__ wqb,
    const u16* __restrict__ wkb, const u16* __restrict__ wvb,
    u16* __restrict__ qb, u16* __restrict__ kb, u16* __restrict__ vT) {
  __shared__ __align__(16) char smA[8192];   // [128][32] bf16, source-chunk-swizzled
  __shared__ __align__(16) char smB[8192];
  const int tid = threadIdx.x;
  const int w = tid >> 6, l = tid & 63;
  const int lm = l & 15, g = l >> 4;
  const int lin = blockIdx.x;                // 0..767
  const int xcd = lin & 7;
  const int kk2 = lin >> 3;                  // 0..95
  const int bx  = xcd * 4 + (kk2 & 3);       // M-tile 0..31
  const int m0 = bx << 7;
  const int j = kk2 >> 2;                    // N-panel 0..23
  const u16* W; u16* dst; int n0, ldc, vmode;
  if (j < 16)      { W = wqb; dst = qb; n0 = j << 7;        ldc = 2048; vmode = 0; }
  else if (j < 20) { W = wkb; dst = kb; n0 = (j - 16) << 7; ldc = 512;  vmode = 0; }
  else             { W = wvb; dst = vT; n0 = (j - 20) << 7; ldc = 0;    vmode = 1; }

  const int srow = w * 16 + (l >> 2);
  const int scol = l & 3;

  f32x4 acc[4][4];
  #pragma unroll
  for (int a = 0; a < 4; ++a)
    #pragma unroll
    for (int bb = 0; bb < 4; ++bb) { f32x4 zz = {0.f, 0.f, 0.f, 0.f}; acc[a][bb] = zz; }

  const int wm = (w >> 1) << 6, wn = (w & 1) << 6;

  for (int k0 = 0; k0 < 2048; k0 += 32) {
    #pragma unroll
    for (int i = 0; i < 2; ++i) {
      const int r = srow + (i << 6);
      const int sc = (scol ^ (r & 3)) << 3;
      gld16(xb + (m0 + r) * 2048 + k0 + sc, smA + ((i * 4 + w) << 10));
      gld16(W  + (n0 + r) * 2048 + k0 + sc, smB + ((i * 4 + w) << 10));
    }
    __syncthreads();
    bf16x8 af[4], bfr[4];
    #pragma unroll
    for (int mt = 0; mt < 4; ++mt) {
      const int row = wm + mt * 16 + lm;
      af[mt] = *(const bf16x8*)(smA + row * 64 + ((g ^ (row & 3)) << 4));
    }
    #pragma unroll
    for (int nt = 0; nt < 4; ++nt) {
      const int row = wn + nt * 16 + lm;
      bfr[nt] = *(const bf16x8*)(smB + row * 64 + ((g ^ (row & 3)) << 4));
    }
    #pragma unroll
    for (int mt = 0; mt < 4; ++mt)
      #pragma unroll
      for (int nt = 0; nt < 4; ++nt)
        acc[mt][nt] = __builtin_amdgcn_mfma_f32_16x16x32_bf16(af[mt], bfr[nt], acc[mt][nt], 0, 0, 0);
    __syncthreads();
  }

  const int gs = ((g & 1) << 1) | (g >> 1);   // token-index bit2<->bit3 swap for vT
  #pragma unroll
  for (int mt = 0; mt < 4; ++mt) {
    #pragma unroll
    for (int nt = 0; nt < 4; ++nt) {
      const int n = n0 + wn + nt * 16 + lm;
      #pragma unroll
      for (int r = 0; r < 4; ++r) {
        const u16 hv = f2b(acc[mt][nt][r]);
        if (!vmode) {
          const int mq = m0 + wm + mt * 16 + g * 4 + r;
          dst[mq * ldc + n] = hv;
        } else {
          const int mv = m0 + wm + mt * 16 + gs * 4 + r;
          dst[n * 4096 + mv] = hv;
        }
      }
    }
  }
}

// ---------------- RMSNorm + RoPE in-place on K ONLY (16384 items) ----------------
// (q's norm+rope is folded into k_attn's Q-load, in-register.)
__global__ __launch_bounds__(256) void k_normrope(u16* __restrict__ kb,
                                                  const float2* __restrict__ cst) {
  const int item = blockIdx.x * 4 + (threadIdx.x >> 6);
  const int l = threadIdx.x & 63;
  u16* p = kb + item * 128;
  const int tpos = (item >> 2) & 2047;
  const float f1 = b2f(p[l]);
  const float f2 = b2f(p[l + 64]);
  float ss = f1 * f1 + f2 * f2;
  #pragma unroll
  for (int d = 1; d < 64; d <<= 1) ss += __shfl_xor(ss, d);
  const float rn = rsqrtf(ss * (1.0f / 128.0f) + 1.1920928955078125e-07f);
  const float2 cs = cst[tpos * 64 + l];
  const float x1 = f1 * rn, x2 = f2 * rn;
  p[l]      = f2b(x1 * cs.x + x2 * cs.y);
  p[l + 64] = f2b(x2 * cs.x - x1 * cs.y);
}

// ---------------- causal GQA flash attention: no-max softmax + kv-split, -------------
// ---------------- pipelined K/V restage (stage issue decoupled from drain) ----------
// Per round: QK (reads K) -> barrier -> issue K-stage(next) -> softmax+PV (reads V,
// K-stage latency hides here) -> barrier (drains K-stage) -> issue V-stage(next)
// (drains under next QK). Same 32KB LDS, same 2 barriers/round, 4 blocks/CU.
// q-RMSNorm+RoPE folded into Q-load; m=0 softmax (|s|<=16.4 bound); kv-split A/B.
__global__ __launch_bounds__(128) void k_attn(
    const u16* __restrict__ qb, const u16* __restrict__ kb,
    const u16* __restrict__ vT, const float2* __restrict__ cst,
    float* __restrict__ out) {
  __shared__ __align__(16) char lds[32768];   // [stream][K 8K | V 8K]
  const int tid = threadIdx.x;
  const int l = tid & 63;
  const int w = tid >> 6;          // wave 0/1 -> q offset 32*w
  const int lq = l & 31;
  const int hi = l >> 5;

  const int bid = blockIdx.x;
  const int cxc = bid & 7;
  const int bb  = cxc >> 2, hkv = cxc & 3;
  const int hsub = (bid >> 3) & 3;
  const int h   = hkv * 4 + hsub;
  const int g   = bid >> 5;              // 0..31, ring = g>>3
  const int a   = g & 7;
  const int tau = (g < 8) ? (31 - a) : (g < 16) ? (16 + a) : (g < 24) ? (15 - a) : a;
  const int RH  = tau + 1;               // double-rounds (each = 2 kv-tiles of 32)
  const int half = RH * 32;              // stream B kv offset

  const u16* kbase = kb + ((size_t)bb * 2048) * 512 + hkv * 128;
  const u16* vbase = vT + ((size_t)(hkv * 128)) * 4096 + (size_t)bb * 2048;
  const u16* qhb   = qb + ((size_t)bb * 2048) * 2048 + h * 128;

  const int krow_t = tid >> 4, kch = tid & 15;   // K staging coords
  const int vrow_t = tid >> 2, vch = tid & 3;    // V staging coords

  const int qabs = tau * 64 + w * 32 + lq;
  const int qmin = tau * 64 + w * 32;

  // ---- Q load + in-register RMSNorm + RoPE (once per block) ----
  bf16x8 qf[8];
  {
    const u16* qp = qhb + (size_t)qabs * 2048;
    bf16x8 qraw[8];
    #pragma unroll
    for (int c = 0; c < 8; ++c) qraw[c] = *(const bf16x8*)(qp + c * 16 + hi * 8);
    float ss = 0.f;
    #pragma unroll
    for (int c = 0; c < 8; ++c)
      #pragma unroll
      for (int jj = 0; jj < 8; ++jj) {
        const float v = (float)qraw[c][jj];
        ss += v * v;
      }
    ss += __shfl_xor(ss, 32);
    const float rn = rsqrtf(ss * (1.0f / 128.0f) + 1.1920928955078125e-07f)
                   * 0.12751742f;   // log2(e)/sqrt(128)
    const float2* cs2 = cst + (size_t)qabs * 64;
    #pragma unroll
    for (int c = 0; c < 4; ++c) {
      u32 wlo[4], whi[4];
      #pragma unroll
      for (int m = 0; m < 4; ++m) {
        float ylo[2], yhi[2];
        #pragma unroll
        for (int p2 = 0; p2 < 2; ++p2) {
          const int jj = 2 * m + p2;
          const int i = c * 16 + hi * 8 + jj;     // 0..63
          const float2 cs = cs2[i];
          const float xlo = (float)qraw[c][jj];
          const float xhi = (float)qraw[c + 4][jj];
          ylo[p2] = (xlo * cs.x + xhi * cs.y) * rn;
          yhi[p2] = (xhi * cs.x - xlo * cs.y) * rn;
        }
        wlo[m] = cvtpk(ylo[0], ylo[1]);
        whi[m] = cvtpk(yhi[0], yhi[1]);
      }
      u32x4 vlo = {wlo[0], wlo[1], wlo[2], wlo[3]};
      u32x4 vhi = {whi[0], whi[1], whi[2], whi[3]};
      qf[c]     = __builtin_bit_cast(bf16x8, vlo);
      qf[c + 4] = __builtin_bit_cast(bf16x8, vhi);
    }
  }

  f32x16 oacc[4], sA, sB;
  #pragma unroll
  for (int dt = 0; dt < 4; ++dt)
    #pragma unroll
    for (int e = 0; e < 16; ++e) oacc[dt][e] = 0.f;
  float llA = 0.f, llB = 0.f;

  // stage K half (4 KB x 2 streams handled by caller loop) / V half separately
  auto STAGE_K = [&](int st, int jb2) {
    char* bK = lds + st * 16384;
    #pragma unroll
    for (int u = 0; u < 4; ++u) {
      const int kr = u * 8 + krow_t;
      gld16(kbase + (size_t)(jb2 + kr) * 512 + ((kch ^ (kr & 15)) << 3),
            bK + u * 2048 + tid * 16);
    }
  };
  auto STAGE_V = [&](int st, int jb2) {
    char* bV = lds + st * 16384 + 8192;
    #pragma unroll
    for (int u = 0; u < 4; ++u) {
      // V paired-row layout: slot (R0, C0) holds V[2*R0 + (cp>>2)][8*(cp&3) ..]
      const int R0 = u * 16 + (vrow_t >> 1);          // 0..63
      const int C0 = ((vrow_t & 1) << 2) + vch;       // 0..7
      const int cp = C0 ^ (R0 & 7);
      const int vd = 2 * R0 + (cp >> 2);              // d row 0..127
      gld16(vbase + (size_t)vd * 4096 + jb2 + ((cp & 3) << 3),
            bV + u * 2048 + tid * 16);
    }
  };

  STAGE_K(0, 0);
  STAGE_V(0, 0);
  STAGE_K(1, half);
  STAGE_V(1, half);
  __syncthreads();

  for (int r = 0; r < RH; ++r) {
    // ---- QK^T for both streams (independent MFMA chains); V-stage drains here ----
    #pragma unroll
    for (int e = 0; e < 16; ++e) { sA[e] = 0.f; sB[e] = 0.f; }
    const char* skA = lds;
    const char* skB = lds + 16384;
    #pragma unroll
    for (int c = 0; c < 8; ++c) {
      const int ch = ((2 * c + hi) ^ (lq & 15)) << 4;
      const bf16x8 kfA = *(const bf16x8*)(skA + lq * 256 + ch);
      const bf16x8 kfB = *(const bf16x8*)(skB + lq * 256 + ch);
      sA = __builtin_amdgcn_mfma_f32_32x32x16_bf16(kfA, qf[c], sA, 0, 0, 0);
      sB = __builtin_amdgcn_mfma_f32_32x32x16_bf16(kfB, qf[c], sB, 0, 0, 0);
    }

    // all waves done reading K; drains prior V-stage before PV reads it
    __syncthreads();
    if (r + 1 < RH) {
      STAGE_K(0, (r + 1) * 32);          // K-stage latency hides under softmax+PV
      STAGE_K(1, half + (r + 1) * 32);
    }

    // ---- no-max softmax: p = exp2(s) (|s| <= 16.4 by RMS-norm bound) ----
    const int jbA = r * 32;
    const int jbB = half + r * 32;
    if (jbA + 31 > qmin) {
      #pragma unroll
      for (int e = 0; e < 16; ++e) {
        const int kvl = (e & 3) + ((e >> 2) << 3) + (hi << 2);
        if (jbA + kvl > qabs) sA[e] = -1e30f;
      }
    }
    if (jbB + 31 > qmin) {
      #pragma unroll
      for (int e = 0; e < 16; ++e) {
        const int kvl = (e & 3) + ((e >> 2) << 3) + (hi << 2);
        if (jbB + kvl > qabs) sB[e] = -1e30f;
      }
    }
    float rA = 0.f, rB = 0.f;
    #pragma unroll
    for (int e = 0; e < 16; e += 4) {
      const float a0 = exp2f(sA[e]),     a1 = exp2f(sA[e + 1]);
      const float a2 = exp2f(sA[e + 2]), a3 = exp2f(sA[e + 3]);
      const float b0 = exp2f(sB[e]),     b1 = exp2f(sB[e + 1]);
      const float b2 = exp2f(sB[e + 2]), b3 = exp2f(sB[e + 3]);
      sA[e] = a0; sA[e + 1] = a1; sA[e + 2] = a2; sA[e + 3] = a3;
      sB[e] = b0; sB[e + 1] = b1; sB[e + 2] = b2; sB[e + 3] = b3;
      rA += (a0 + a1) + (a2 + a3);
      rB += (b0 + b1) + (b2 + b3);
    }
    llA += rA; llB += rB;

    // ---- PV for both streams into shared oacc (additive merge) ----
    // Exchange-free: B-fragment = lane's own P values in order (vT pre-permuted).
    const char* svA = lds + 8192;
    const char* svB = lds + 16384 + 8192;
    #pragma unroll
    for (int cc = 0; cc < 2; ++cc) {
      const int c8 = cc * 8;
      u32x4 bwA, bwB;
      bwA.x = cvtpk(sA[c8 + 0], sA[c8 + 1]);
      bwA.y = cvtpk(sA[c8 + 2], sA[c8 + 3]);
      bwA.z = cvtpk(sA[c8 + 4], sA[c8 + 5]);
      bwA.w = cvtpk(sA[c8 + 6], sA[c8 + 7]);
      bwB.x = cvtpk(sB[c8 + 0], sB[c8 + 1]);
      bwB.y = cvtpk(sB[c8 + 2], sB[c8 + 3]);
      bwB.z = cvtpk(sB[c8 + 4], sB[c8 + 5]);
      bwB.w = cvtpk(sB[c8 + 6], sB[c8 + 7]);
      const bf16x8 pfA = __builtin_bit_cast(bf16x8, bwA);
      const bf16x8 pfB = __builtin_bit_cast(bf16x8, bwB);
      #pragma unroll
      for (int dt = 0; dt < 4; ++dt) {
        const int vrow = dt * 16 + (lq >> 1);
        const int cpre = ((lq & 1) << 2) + 2 * cc + hi;
        const int chv = (cpre ^ (vrow & 7)) << 4;
        const bf16x8 vfA = *(const bf16x8*)(svA + vrow * 128 + chv);
        oacc[dt] = __builtin_amdgcn_mfma_f32_32x32x16_bf16(vfA, pfA, oacc[dt], 0, 0, 0);
      }
      #pragma unroll
      for (int dt = 0; dt < 4; ++dt) {
        const int vrow = dt * 16 + (lq >> 1);
        const int cpre = ((lq & 1) << 2) + 2 * cc + hi;
        const int chv = (cpre ^ (vrow & 7)) << 4;
        const bf16x8 vfB = *(const bf16x8*)(svB + vrow * 128 + chv);
        oacc[dt] = __builtin_amdgcn_mfma_f32_32x32x16_bf16(vfB, pfB, oacc[dt], 0, 0, 0);
      }
    }

    // all waves done reading V; drains K-stage before next QK reads it
    __syncthreads();
    if (r + 1 < RH) {
      STAGE_V(0, (r + 1) * 32);          // V-stage latency hides under next QK
      STAGE_V(1, half + (r + 1) * 32);
    }
  }

  // ---- epilogue: merge streams + halves, write O ----
  float ll = llA + llB;
  ll += __shfl_xor(ll, 32);
  const float inv = 1.0f / ll;
  float* ob = out + ((size_t)(bb * 2048 + qabs)) * 2048 + h * 128;
  #pragma unroll
  for (int dt = 0; dt < 4; ++dt)
    #pragma unroll
    for (int qd = 0; qd < 4; ++qd) {
      float4 o4;
      o4.x = oacc[dt][qd * 4 + 0] * inv;
      o4.y = oacc[dt][qd * 4 + 1] * inv;
      o4.z = oacc[dt][qd * 4 + 2] * inv;
      o4.w = oacc[dt][qd * 4 + 3] * inv;
      *(float4*)(ob + dt * 32 + qd * 8 + hi * 4) = o4;
    }
}

extern "C" void kernel_launch(void* const* d_in, const int* in_sizes, int n_in,
                              void* d_out, int out_size, void* d_ws, size_t ws_size,
                              hipStream_t stream) {
  const float* x  = (const float*)d_in[0];
  const float* wq = (const float*)d_in[1];
  const float* wk = (const float*)d_in[2];
  const float* wv = (const float*)d_in[3];
  float* out = (float*)d_out;
  char* ws = (char*)d_ws;

  float2* cst = (float2*)(ws);                // 1 MB packed {cos,sin}
  u16* xb  = (u16*)(ws + 1048576);            // 16 MB
  u16* wqb = (u16*)(ws + 17825792);           // 8 MB
  u16* wkb = (u16*)(ws + 26214400);           // 2 MB
  u16* wvb = (u16*)(ws + 28311552);           // 2 MB
  u16* qb  = (u16*)(ws + 30408704);           // 16 MB
  u16* kb  = (u16*)(ws + 47185920);           // 4 MB
  u16* vT  = (u16*)(ws + 51380224);           // 4 MB  -> total 55574528
  if (ws_size < 55574528) return;

  k_prep    <<<dim3(14848), dim3(256), 0, stream>>>(x, wq, wk, wv, xb, wqb, wkb, wvb, cst);
  k_gemm    <<<dim3(768),   dim3(256), 0, stream>>>(xb, wqb, wkb, wvb, qb, kb, vT);
  k_normrope<<<dim3(4096),  dim3(256), 0, stream>>>(kb, cst);
  k_attn    <<<dim3(1024),  dim3(128), 0, stream>>>(qb, kb, vT, cst, out);
}